// Round 1
// baseline (1622.530 us; speedup 1.0000x reference)
//
#include <hip/hip_runtime.h>
#include <hip/hip_bf16.h>

#define NN 100000
#define EE 3200000
#define NF 128
#define NH 256
#define NC 16

typedef __bf16 bf16x8 __attribute__((ext_vector_type(8)));
typedef float f32x4 __attribute__((ext_vector_type(4)));

static __device__ __forceinline__ unsigned short f2bf(float f) {
    unsigned int u = __builtin_bit_cast(unsigned int, f);
    u += 0x7FFFu + ((u >> 16) & 1u);
    return (unsigned short)(u >> 16);
}
static __device__ __forceinline__ float b2f(unsigned short h) {
    unsigned int u = ((unsigned int)h) << 16;
    return __builtin_bit_cast(float, u);
}

// ---------- f32 -> bf16 convert (vector x4) ----------
__global__ void k_cvt_bf16(const float* __restrict__ in, unsigned short* __restrict__ out, int n) {
    int i = (blockIdx.x * blockDim.x + threadIdx.x) * 4;
    if (i + 3 < n) {
        float4 v = *(const float4*)(in + i);
        ushort4 o;
        o.x = f2bf(v.x); o.y = f2bf(v.y); o.z = f2bf(v.z); o.w = f2bf(v.w);
        *(ushort4*)(out + i) = o;
    } else {
        for (int t = 0; t < 4 && i + t < n; ++t) out[i + t] = f2bf(in[i + t]);
    }
}

// ---------- W[K,C] f32 -> Wt[C,K] bf16 (transpose for MFMA B-frag contiguity) ----------
__global__ void k_wT(const float* __restrict__ W, unsigned short* __restrict__ Wt, int K, int C) {
    int i = blockIdx.x * blockDim.x + threadIdx.x;
    if (i < K * C) {
        int k = i / C, c = i % C;
        Wt[c * K + k] = f2bf(W[i]);
    }
}

// ---------- CSR build ----------
__global__ void k_hist(const int* __restrict__ row, int* __restrict__ counts, int e) {
    int i = blockIdx.x * blockDim.x + threadIdx.x;
    if (i < e) atomicAdd(&counts[row[i]], 1);
}

__global__ void k_scan1(const int* __restrict__ counts, int* __restrict__ scanb,
                        int* __restrict__ parts, int n) {
    __shared__ int lds[256];
    int tid = threadIdx.x;
    int base = blockIdx.x * 1024 + tid * 4;
    int v[4]; int s = 0;
    for (int t = 0; t < 4; ++t) { v[t] = (base + t < n) ? counts[base + t] : 0; s += v[t]; }
    lds[tid] = s; __syncthreads();
    for (int off = 1; off < 256; off <<= 1) {
        int add = (tid >= off) ? lds[tid - off] : 0;
        __syncthreads();
        lds[tid] += add;
        __syncthreads();
    }
    int incl = lds[tid];
    int run = incl - s;
    for (int t = 0; t < 4; ++t) { run += v[t]; if (base + t < n) scanb[base + t] = run; }
    if (tid == 255) parts[blockIdx.x] = incl;
}

__global__ void k_scan2(int* __restrict__ parts, int np) {
    __shared__ int lds[128];
    int tid = threadIdx.x;
    int v = (tid < np) ? parts[tid] : 0;
    lds[tid] = v; __syncthreads();
    for (int off = 1; off < 128; off <<= 1) {
        int add = (tid >= off) ? lds[tid - off] : 0;
        __syncthreads();
        lds[tid] += add;
        __syncthreads();
    }
    parts[tid] = lds[tid] - v;  // exclusive
}

__global__ void k_scan3(const int* __restrict__ scanb, const int* __restrict__ parts,
                        const int* __restrict__ counts, int* __restrict__ rowp,
                        int* __restrict__ cursor, int n) {
    int i = blockIdx.x * blockDim.x + threadIdx.x;
    if (i < n) {
        int val = scanb[i] + parts[i >> 10];
        rowp[i + 1] = val;
        cursor[i] = val - counts[i];
        if (i == 0) rowp[0] = 0;
    }
}

__global__ void k_scatter(const int* __restrict__ row, const int* __restrict__ col,
                          const float* __restrict__ val, int* __restrict__ cursor,
                          int* __restrict__ colS, float* __restrict__ valS, int e) {
    int i = blockIdx.x * blockDim.x + threadIdx.x;
    if (i < e) {
        int r = row[i];
        int pos = atomicAdd(&cursor[r], 1);
        colS[pos] = col[i];
        valS[pos] = val[i];
    }
}

// ---------- MFMA bf16 GEMM: C[M,256] = A[M,K] @ Bt[256,K]^T ----------
// block = 256 threads (4 waves); block tile 64 rows x 256 cols; wave: 64 rows x 64 cols
__global__ __launch_bounds__(256) void k_gemm(const unsigned short* __restrict__ A,
                                              const unsigned short* __restrict__ Bt,
                                              unsigned short* __restrict__ C,
                                              int M, int K) {
    int wave = threadIdx.x >> 6, lane = threadIdx.x & 63;
    int row0 = blockIdx.x * 64;
    int colBase = wave * 64;
    int hr = lane & 15, kg = lane >> 4;  // half-row (0..15), k-group (0..3)
    f32x4 acc[4][4];
#pragma unroll
    for (int r = 0; r < 4; ++r)
#pragma unroll
        for (int c = 0; c < 4; ++c) acc[r][c] = (f32x4){0.f, 0.f, 0.f, 0.f};

    for (int k0 = 0; k0 < K; k0 += 32) {
        int kk = k0 + kg * 8;
        bf16x8 af[4], bf_[4];
#pragma unroll
        for (int r = 0; r < 4; ++r) {
            int ar = row0 + r * 16 + hr;
            if (ar >= M) ar = M - 1;
            af[r] = *(const bf16x8*)(A + (size_t)ar * K + kk);
        }
#pragma unroll
        for (int c = 0; c < 4; ++c) {
            int bc = colBase + c * 16 + hr;
            bf_[c] = *(const bf16x8*)(Bt + (size_t)bc * K + kk);
        }
#pragma unroll
        for (int r = 0; r < 4; ++r)
#pragma unroll
            for (int c = 0; c < 4; ++c)
                acc[r][c] = __builtin_amdgcn_mfma_f32_16x16x32_bf16(af[r], bf_[c], acc[r][c], 0, 0, 0);
    }
    // C/D layout: col = lane&15, row = (lane>>4)*4 + reg   [measured m89/m91]
#pragma unroll
    for (int r = 0; r < 4; ++r)
#pragma unroll
        for (int c = 0; c < 4; ++c) {
            int col = colBase + c * 16 + hr;
#pragma unroll
            for (int i = 0; i < 4; ++i) {
                int rr = row0 + r * 16 + kg * 4 + i;
                if (rr < M) C[(size_t)rr * 256 + col] = f2bf(acc[r][c][i]);
            }
        }
}

// ---------- SpMM: out[row] = relu(sum_e val*S[col_e] + bias), wave per row ----------
__global__ __launch_bounds__(256) void k_spmm(const int* __restrict__ rowp,
                                              const int* __restrict__ cols,
                                              const float* __restrict__ vals,
                                              const unsigned short* __restrict__ S,
                                              const float* __restrict__ bias,
                                              unsigned short* __restrict__ Hout, int n) {
    int lane = threadIdx.x & 63;
    int row = blockIdx.x * 4 + (threadIdx.x >> 6);
    if (row >= n) return;
    int s = rowp[row], e = rowp[row + 1];
    int f = lane * 4;
    float a0 = 0.f, a1 = 0.f, a2 = 0.f, a3 = 0.f;
#pragma unroll 4
    for (int i = s; i < e; ++i) {
        int c = cols[i];
        float v = vals[i];
        ushort4 t = *(const ushort4*)(S + (size_t)c * 256 + f);
        a0 += v * b2f(t.x); a1 += v * b2f(t.y); a2 += v * b2f(t.z); a3 += v * b2f(t.w);
    }
    a0 = fmaxf(a0 + bias[f], 0.f);
    a1 = fmaxf(a1 + bias[f + 1], 0.f);
    a2 = fmaxf(a2 + bias[f + 2], 0.f);
    a3 = fmaxf(a3 + bias[f + 3], 0.f);
    ushort4 o; o.x = f2bf(a0); o.y = f2bf(a1); o.z = f2bf(a2); o.w = f2bf(a3);
    *(ushort4*)(Hout + (size_t)row * 256 + f) = o;
}

// ---------- FC + log_softmax: 16 lanes per node, 4 nodes per wave ----------
__global__ __launch_bounds__(256) void k_fc_lsm(const unsigned short* __restrict__ H,
                                                const float* __restrict__ Wf,
                                                const float* __restrict__ bf,
                                                float* __restrict__ out, int n) {
    int lane = threadIdx.x & 63;
    int wave = threadIdx.x >> 6;
    int sub = lane >> 4, j = lane & 15;
    int node = (blockIdx.x * 4 + wave) * 4 + sub;
    bool valid = node < n;
    int nd = valid ? node : (n - 1);
    float acc = 0.f;
    for (int f0 = 0; f0 < NH; f0 += 8) {
        union { uint4 u; unsigned short s[8]; } h;
        h.u = *(const uint4*)(H + (size_t)nd * NH + f0);
#pragma unroll
        for (int t = 0; t < 8; ++t) acc += b2f(h.s[t]) * Wf[(f0 + t) * NC + j];
    }
    acc += bf[j];
    float mx = acc;
    for (int m = 1; m < 16; m <<= 1) mx = fmaxf(mx, __shfl_xor(mx, m, 16));
    float sm = __expf(acc - mx);
    for (int m = 1; m < 16; m <<= 1) sm += __shfl_xor(sm, m, 16);
    float res = acc - mx - __logf(sm);
    if (valid) out[(size_t)node * NC + j] = res;
}

extern "C" void kernel_launch(void* const* d_in, const int* in_sizes, int n_in,
                              void* d_out, int out_size, void* d_ws, size_t ws_size,
                              hipStream_t stream) {
    const float* x      = (const float*)d_in[0];
    const float* adjval = (const float*)d_in[1];
    const float* w1 = (const float*)d_in[2];  const float* b1 = (const float*)d_in[3];
    const float* w2 = (const float*)d_in[4];  const float* b2 = (const float*)d_in[5];
    const float* w3 = (const float*)d_in[6];  const float* b3 = (const float*)d_in[7];
    const float* w4 = (const float*)d_in[8];  const float* b4 = (const float*)d_in[9];
    const float* fcw = (const float*)d_in[10]; const float* fcb = (const float*)d_in[11];
    const int* arow = (const int*)d_in[12];
    const int* acol = (const int*)d_in[13];
    float* out = (float*)d_out;

    char* ws = (char*)d_ws;
    size_t off = 0;
    auto alloc = [&](size_t bytes) { size_t o = off; off += (bytes + 255) & ~(size_t)255; return o; };

    unsigned short* xb  = (unsigned short*)(ws + alloc((size_t)NN * NF * 2));
    unsigned short* Sb  = (unsigned short*)(ws + alloc((size_t)NN * NH * 2));
    unsigned short* H1  = (unsigned short*)(ws + alloc((size_t)NN * NH * 2));
    unsigned short* H2  = (unsigned short*)(ws + alloc((size_t)NN * NH * 2));
    unsigned short* Wt1 = (unsigned short*)(ws + alloc((size_t)NH * NF * 2));
    unsigned short* Wt2 = (unsigned short*)(ws + alloc((size_t)NH * NH * 2));
    unsigned short* Wt3 = (unsigned short*)(ws + alloc((size_t)NH * NH * 2));
    unsigned short* Wt4 = (unsigned short*)(ws + alloc((size_t)NH * NH * 2));
    int*   counts = (int*)(ws + alloc((size_t)NN * 4));
    int*   scanb  = (int*)(ws + alloc((size_t)NN * 4));
    int*   parts  = (int*)(ws + alloc(128 * 4));
    int*   rowp   = (int*)(ws + alloc(((size_t)NN + 1) * 4));
    int*   cursor = (int*)(ws + alloc((size_t)NN * 4));
    int*   colS   = (int*)(ws + alloc((size_t)EE * 4));
    float* valS   = (float*)(ws + alloc((size_t)EE * 4));

    // --- input conversions ---
    k_cvt_bf16<<<(NN * NF / 4 + 255) / 256, 256, 0, stream>>>(x, xb, NN * NF);
    k_wT<<<(NF * NH + 255) / 256, 256, 0, stream>>>(w1, Wt1, NF, NH);
    k_wT<<<(NH * NH + 255) / 256, 256, 0, stream>>>(w2, Wt2, NH, NH);
    k_wT<<<(NH * NH + 255) / 256, 256, 0, stream>>>(w3, Wt3, NH, NH);
    k_wT<<<(NH * NH + 255) / 256, 256, 0, stream>>>(w4, Wt4, NH, NH);

    // --- CSR build ---
    hipMemsetAsync(counts, 0, (size_t)NN * 4, stream);
    k_hist<<<(EE + 255) / 256, 256, 0, stream>>>(arow, counts, EE);
    int nscan = (NN + 1023) / 1024;  // 98
    k_scan1<<<nscan, 256, 0, stream>>>(counts, scanb, parts, NN);
    k_scan2<<<1, 128, 0, stream>>>(parts, nscan);
    k_scan3<<<(NN + 255) / 256, 256, 0, stream>>>(scanb, parts, counts, rowp, cursor, NN);
    k_scatter<<<(EE + 255) / 256, 256, 0, stream>>>(arow, acol, adjval, cursor, colS, valS, EE);

    int gGemm = (NN + 63) / 64;     // 1563
    int gSpmm = (NN + 3) / 4;       // 25000
    // --- layer 1 ---
    k_gemm<<<gGemm, 256, 0, stream>>>(xb, Wt1, Sb, NN, NF);
    k_spmm<<<gSpmm, 256, 0, stream>>>(rowp, colS, valS, Sb, b1, H1, NN);
    // --- layer 2 ---
    k_gemm<<<gGemm, 256, 0, stream>>>(H1, Wt2, Sb, NN, NH);
    k_spmm<<<gSpmm, 256, 0, stream>>>(rowp, colS, valS, Sb, b2, H2, NN);
    // --- layer 3 ---
    k_gemm<<<gGemm, 256, 0, stream>>>(H2, Wt3, Sb, NN, NH);
    k_spmm<<<gSpmm, 256, 0, stream>>>(rowp, colS, valS, Sb, b3, H1, NN);
    // --- layer 4 ---
    k_gemm<<<gGemm, 256, 0, stream>>>(H1, Wt4, Sb, NN, NH);
    k_spmm<<<gSpmm, 256, 0, stream>>>(rowp, colS, valS, Sb, b4, H2, NN);
    // --- FC + log_softmax ---
    k_fc_lsm<<<(NN + 15) / 16, 256, 0, stream>>>(H2, fcw, fcb, out, NN);
}

// Round 2
// 1475.725 us; speedup vs baseline: 1.0995x; 1.0995x over previous
//
#include <hip/hip_runtime.h>
#include <hip/hip_bf16.h>

#define NN 100000
#define EE 3200000
#define NF 128
#define NH 256
#define NC 16

typedef __bf16 bf16x8 __attribute__((ext_vector_type(8)));
typedef float f32x4 __attribute__((ext_vector_type(4)));

static __device__ __forceinline__ unsigned short f2bf(float f) {
    unsigned int u = __builtin_bit_cast(unsigned int, f);
    u += 0x7FFFu + ((u >> 16) & 1u);
    return (unsigned short)(u >> 16);
}
static __device__ __forceinline__ float b2f(unsigned short h) {
    unsigned int u = ((unsigned int)h) << 16;
    return __builtin_bit_cast(float, u);
}

// ---------- f32 -> bf16 convert (vector x4) ----------
__global__ void k_cvt_bf16(const float* __restrict__ in, unsigned short* __restrict__ out, int n) {
    int i = (blockIdx.x * blockDim.x + threadIdx.x) * 4;
    if (i + 3 < n) {
        float4 v = *(const float4*)(in + i);
        ushort4 o;
        o.x = f2bf(v.x); o.y = f2bf(v.y); o.z = f2bf(v.z); o.w = f2bf(v.w);
        *(ushort4*)(out + i) = o;
    } else {
        for (int t = 0; t < 4 && i + t < n; ++t) out[i + t] = f2bf(in[i + t]);
    }
}

// ---------- W[K,C] f32 -> Wt[C,K] bf16 ----------
__global__ void k_wT(const float* __restrict__ W, unsigned short* __restrict__ Wt, int K, int C) {
    int i = blockIdx.x * blockDim.x + threadIdx.x;
    if (i < K * C) {
        int k = i / C, c = i % C;
        Wt[c * K + k] = f2bf(W[i]);
    }
}

// ---------- CSR build ----------
__global__ void k_hist(const int* __restrict__ row, int* __restrict__ counts, int e) {
    int i = blockIdx.x * blockDim.x + threadIdx.x;
    if (i < e) atomicAdd(&counts[row[i]], 1);
}

__global__ void k_scan1(const int* __restrict__ counts, int* __restrict__ scanb,
                        int* __restrict__ parts, int n) {
    __shared__ int lds[256];
    int tid = threadIdx.x;
    int base = blockIdx.x * 1024 + tid * 4;
    int v[4]; int s = 0;
    for (int t = 0; t < 4; ++t) { v[t] = (base + t < n) ? counts[base + t] : 0; s += v[t]; }
    lds[tid] = s; __syncthreads();
    for (int off = 1; off < 256; off <<= 1) {
        int add = (tid >= off) ? lds[tid - off] : 0;
        __syncthreads();
        lds[tid] += add;
        __syncthreads();
    }
    int incl = lds[tid];
    int run = incl - s;
    for (int t = 0; t < 4; ++t) { run += v[t]; if (base + t < n) scanb[base + t] = run; }
    if (tid == 255) parts[blockIdx.x] = incl;
}

__global__ void k_scan2(int* __restrict__ parts, int np) {
    __shared__ int lds[128];
    int tid = threadIdx.x;
    int v = (tid < np) ? parts[tid] : 0;
    lds[tid] = v; __syncthreads();
    for (int off = 1; off < 128; off <<= 1) {
        int add = (tid >= off) ? lds[tid - off] : 0;
        __syncthreads();
        lds[tid] += add;
        __syncthreads();
    }
    parts[tid] = lds[tid] - v;  // exclusive
}

__global__ void k_scan3(const int* __restrict__ scanb, const int* __restrict__ parts,
                        const int* __restrict__ counts, int* __restrict__ rowp,
                        int* __restrict__ cursor, int n) {
    int i = blockIdx.x * blockDim.x + threadIdx.x;
    if (i < n) {
        int val = scanb[i] + parts[i >> 10];
        rowp[i + 1] = val;
        cursor[i] = val - counts[i];
        if (i == 0) rowp[0] = 0;
    }
}

// scatter packed (col, val) as one 8B store — halves scattered-store count
__global__ void k_scatter(const int* __restrict__ row, const int* __restrict__ col,
                          const float* __restrict__ val, int* __restrict__ cursor,
                          unsigned long long* __restrict__ pairs, int e) {
    int i = blockIdx.x * blockDim.x + threadIdx.x;
    if (i < e) {
        int r = row[i];
        unsigned long long p = ((unsigned long long)__builtin_bit_cast(unsigned int, val[i]) << 32)
                             | (unsigned int)col[i];
        int pos = atomicAdd(&cursor[r], 1);
        pairs[pos] = p;
    }
}

// ---------- MFMA bf16 GEMM: C[M,256] = A[M,K] @ Bt[256,K]^T, optional bias+relu ----------
template <bool BR>
__global__ __launch_bounds__(256) void k_gemm(const unsigned short* __restrict__ A,
                                              const unsigned short* __restrict__ Bt,
                                              const float* __restrict__ bias,
                                              unsigned short* __restrict__ C,
                                              int M, int K) {
    int wave = threadIdx.x >> 6, lane = threadIdx.x & 63;
    int row0 = blockIdx.x * 64;
    int colBase = wave * 64;
    int hr = lane & 15, kg = lane >> 4;
    f32x4 acc[4][4];
#pragma unroll
    for (int r = 0; r < 4; ++r)
#pragma unroll
        for (int c = 0; c < 4; ++c) acc[r][c] = (f32x4){0.f, 0.f, 0.f, 0.f};

    for (int k0 = 0; k0 < K; k0 += 32) {
        int kk = k0 + kg * 8;
        bf16x8 af[4], bf_[4];
#pragma unroll
        for (int r = 0; r < 4; ++r) {
            int ar = row0 + r * 16 + hr;
            if (ar >= M) ar = M - 1;
            af[r] = *(const bf16x8*)(A + (size_t)ar * K + kk);
        }
#pragma unroll
        for (int c = 0; c < 4; ++c) {
            int bc = colBase + c * 16 + hr;
            bf_[c] = *(const bf16x8*)(Bt + (size_t)bc * K + kk);
        }
#pragma unroll
        for (int r = 0; r < 4; ++r)
#pragma unroll
            for (int c = 0; c < 4; ++c)
                acc[r][c] = __builtin_amdgcn_mfma_f32_16x16x32_bf16(af[r], bf_[c], acc[r][c], 0, 0, 0);
    }
    // C/D layout: col = lane&15, row = (lane>>4)*4 + reg
#pragma unroll
    for (int r = 0; r < 4; ++r)
#pragma unroll
        for (int c = 0; c < 4; ++c) {
            int col = colBase + c * 16 + hr;
            float bv = BR ? bias[col] : 0.f;
#pragma unroll
            for (int i = 0; i < 4; ++i) {
                int rr = row0 + r * 16 + kg * 4 + i;
                float v = acc[r][c][i];
                if (BR) v = fmaxf(v + bv, 0.f);
                if (rr < M) C[(size_t)rr * 256 + col] = f2bf(v);
            }
        }
}

// ---------- SpMM D=256: out[row] = relu(sum val*S[col] + bias) ----------
__global__ __launch_bounds__(256) void k_spmm256(const int* __restrict__ rowp,
                                                 const unsigned long long* __restrict__ pairs,
                                                 const unsigned short* __restrict__ S,
                                                 const float* __restrict__ bias,
                                                 unsigned short* __restrict__ Hout, int n) {
    int lane = threadIdx.x & 63;
    int row = blockIdx.x * 4 + (threadIdx.x >> 6);
    if (row >= n) return;
    int s = rowp[row], e = rowp[row + 1];
    int f = lane * 4;
    float a0 = 0.f, a1 = 0.f, a2 = 0.f, a3 = 0.f;
#pragma unroll 4
    for (int i = s; i < e; ++i) {
        unsigned long long p = pairs[i];
        int c = (int)(unsigned int)p;
        float v = __builtin_bit_cast(float, (unsigned int)(p >> 32));
        ushort4 t = *(const ushort4*)(S + (size_t)c * 256 + f);
        a0 += v * b2f(t.x); a1 += v * b2f(t.y); a2 += v * b2f(t.z); a3 += v * b2f(t.w);
    }
    a0 = fmaxf(a0 + bias[f], 0.f);
    a1 = fmaxf(a1 + bias[f + 1], 0.f);
    a2 = fmaxf(a2 + bias[f + 2], 0.f);
    a3 = fmaxf(a3 + bias[f + 3], 0.f);
    ushort4 o; o.x = f2bf(a0); o.y = f2bf(a1); o.z = f2bf(a2); o.w = f2bf(a3);
    *(ushort4*)(Hout + (size_t)row * 256 + f) = o;
}

// ---------- SpMM D=128, no bias/relu: out[row] = sum val*X[col] (layer-1 aggregation) ----------
__global__ __launch_bounds__(256) void k_spmm128(const int* __restrict__ rowp,
                                                 const unsigned long long* __restrict__ pairs,
                                                 const unsigned short* __restrict__ X,
                                                 unsigned short* __restrict__ Out, int n) {
    int lane = threadIdx.x & 63;
    int row = blockIdx.x * 4 + (threadIdx.x >> 6);
    if (row >= n) return;
    int s = rowp[row], e = rowp[row + 1];
    int f = lane * 2;
    float a0 = 0.f, a1 = 0.f;
#pragma unroll 4
    for (int i = s; i < e; ++i) {
        unsigned long long p = pairs[i];
        int c = (int)(unsigned int)p;
        float v = __builtin_bit_cast(float, (unsigned int)(p >> 32));
        ushort2 t = *(const ushort2*)(X + (size_t)c * 128 + f);
        a0 += v * b2f(t.x); a1 += v * b2f(t.y);
    }
    ushort2 o; o.x = f2bf(a0); o.y = f2bf(a1);
    *(ushort2*)(Out + (size_t)row * 128 + f) = o;
}

// ---------- FC + log_softmax: 16 lanes per node ----------
__global__ __launch_bounds__(256) void k_fc_lsm(const unsigned short* __restrict__ H,
                                                const float* __restrict__ Wf,
                                                const float* __restrict__ bf,
                                                float* __restrict__ out, int n) {
    int lane = threadIdx.x & 63;
    int wave = threadIdx.x >> 6;
    int sub = lane >> 4, j = lane & 15;
    int node = (blockIdx.x * 4 + wave) * 4 + sub;
    bool valid = node < n;
    int nd = valid ? node : (n - 1);
    float acc = 0.f;
    for (int f0 = 0; f0 < NH; f0 += 8) {
        union { uint4 u; unsigned short s[8]; } h;
        h.u = *(const uint4*)(H + (size_t)nd * NH + f0);
#pragma unroll
        for (int t = 0; t < 8; ++t) acc += b2f(h.s[t]) * Wf[(f0 + t) * NC + j];
    }
    acc += bf[j];
    float mx = acc;
    for (int m = 1; m < 16; m <<= 1) mx = fmaxf(mx, __shfl_xor(mx, m, 16));
    float sm = __expf(acc - mx);
    for (int m = 1; m < 16; m <<= 1) sm += __shfl_xor(sm, m, 16);
    float res = acc - mx - __logf(sm);
    if (valid) out[(size_t)node * NC + j] = res;
}

extern "C" void kernel_launch(void* const* d_in, const int* in_sizes, int n_in,
                              void* d_out, int out_size, void* d_ws, size_t ws_size,
                              hipStream_t stream) {
    const float* x      = (const float*)d_in[0];
    const float* adjval = (const float*)d_in[1];
    const float* w1 = (const float*)d_in[2];  const float* b1 = (const float*)d_in[3];
    const float* w2 = (const float*)d_in[4];  const float* b2 = (const float*)d_in[5];
    const float* w3 = (const float*)d_in[6];  const float* b3 = (const float*)d_in[7];
    const float* w4 = (const float*)d_in[8];  const float* b4 = (const float*)d_in[9];
    const float* fcw = (const float*)d_in[10]; const float* fcb = (const float*)d_in[11];
    const int* arow = (const int*)d_in[12];
    const int* acol = (const int*)d_in[13];
    float* out = (float*)d_out;

    char* ws = (char*)d_ws;
    size_t off = 0;
    auto alloc = [&](size_t bytes) { size_t o = off; off += (bytes + 255) & ~(size_t)255; return o; };

    unsigned short* xb  = (unsigned short*)(ws + alloc((size_t)NN * NF * 2));
    unsigned short* Sb  = (unsigned short*)(ws + alloc((size_t)NN * NH * 2));  // also holds Ax [N,128] for layer 1
    unsigned short* H1  = (unsigned short*)(ws + alloc((size_t)NN * NH * 2));
    unsigned short* H2  = (unsigned short*)(ws + alloc((size_t)NN * NH * 2));
    unsigned short* Wt1 = (unsigned short*)(ws + alloc((size_t)NH * NF * 2));
    unsigned short* Wt2 = (unsigned short*)(ws + alloc((size_t)NH * NH * 2));
    unsigned short* Wt3 = (unsigned short*)(ws + alloc((size_t)NH * NH * 2));
    unsigned short* Wt4 = (unsigned short*)(ws + alloc((size_t)NH * NH * 2));
    int*   counts = (int*)(ws + alloc((size_t)NN * 4));
    int*   scanb  = (int*)(ws + alloc((size_t)NN * 4));
    int*   parts  = (int*)(ws + alloc(128 * 4));
    int*   rowp   = (int*)(ws + alloc(((size_t)NN + 1) * 4));
    int*   cursor = (int*)(ws + alloc((size_t)NN * 4));
    unsigned long long* pairs = (unsigned long long*)(ws + alloc((size_t)EE * 8));

    // --- input conversions ---
    k_cvt_bf16<<<(NN * NF / 4 + 255) / 256, 256, 0, stream>>>(x, xb, NN * NF);
    k_wT<<<(NF * NH + 255) / 256, 256, 0, stream>>>(w1, Wt1, NF, NH);
    k_wT<<<(NH * NH + 255) / 256, 256, 0, stream>>>(w2, Wt2, NH, NH);
    k_wT<<<(NH * NH + 255) / 256, 256, 0, stream>>>(w3, Wt3, NH, NH);
    k_wT<<<(NH * NH + 255) / 256, 256, 0, stream>>>(w4, Wt4, NH, NH);

    // --- CSR build ---
    hipMemsetAsync(counts, 0, (size_t)NN * 4, stream);
    k_hist<<<(EE + 255) / 256, 256, 0, stream>>>(arow, counts, EE);
    int nscan = (NN + 1023) / 1024;  // 98
    k_scan1<<<nscan, 256, 0, stream>>>(counts, scanb, parts, NN);
    k_scan2<<<1, 128, 0, stream>>>(parts, nscan);
    k_scan3<<<(NN + 255) / 256, 256, 0, stream>>>(scanb, parts, counts, rowp, cursor, NN);
    k_scatter<<<(EE + 255) / 256, 256, 0, stream>>>(arow, acol, adjval, cursor, pairs, EE);

    int gGemm = (NN + 63) / 64;     // 1563
    int gSpmm = (NN + 3) / 4;       // 25000
    // --- layer 1 (reordered: (A@x)@W1, gathers 128 feats instead of 256) ---
    k_spmm128<<<gSpmm, 256, 0, stream>>>(rowp, pairs, xb, Sb, NN);
    k_gemm<true><<<gGemm, 256, 0, stream>>>(Sb, Wt1, b1, H1, NN, NF);
    // --- layer 2 ---
    k_gemm<false><<<gGemm, 256, 0, stream>>>(H1, Wt2, nullptr, Sb, NN, NH);
    k_spmm256<<<gSpmm, 256, 0, stream>>>(rowp, pairs, Sb, b2, H2, NN);
    // --- layer 3 ---
    k_gemm<false><<<gGemm, 256, 0, stream>>>(H2, Wt3, nullptr, Sb, NN, NH);
    k_spmm256<<<gSpmm, 256, 0, stream>>>(rowp, pairs, Sb, b3, H1, NN);
    // --- layer 4 ---
    k_gemm<false><<<gGemm, 256, 0, stream>>>(H1, Wt4, nullptr, Sb, NN, NH);
    k_spmm256<<<gSpmm, 256, 0, stream>>>(rowp, pairs, Sb, b4, H2, NN);
    // --- FC + log_softmax ---
    k_fc_lsm<<<(NN + 15) / 16, 256, 0, stream>>>(H2, fcw, fcb, out, NN);
}